// Round 7
// baseline (7916.966 us; speedup 1.0000x reference)
//
#include <hip/hip_runtime.h>
#include <math.h>

static constexpr int B_ = 512;
static constexpr int T_ = 16;
static constexpr int S_ = 64;
static constexpr int K_ = 32;
static constexpr int N_ = 1024;   // T_*S_

// ---------------- init: rowmap identity + logdet zero ----------------
__global__ void initk(int* __restrict__ rowmap, float* __restrict__ logdet) {
  int idx = blockIdx.x * 256 + threadIdx.x;
  if (idx < K_ * N_) rowmap[idx] = idx & (N_ - 1);
  if (idx < K_) logdet[idx] = 0.f;
}

// ---------------- build block-Toeplitz M[k][row][col], LDS-transpose version ----
// block (i=by rows, j=bx cols): M_block = A[i-j]^T if i >= j else A[j-i]
__global__ __launch_bounds__(256) void buildM(const float* __restrict__ A, float* __restrict__ M) {
  int k = blockIdx.z, i = blockIdx.y, j = blockIdx.x;
  int d = i - j;
  int ad = d >= 0 ? d : -d;
  const float* Ad = A + ((size_t)(ad * K_ + k) << 12);
  float* out = M + ((size_t)k << 20) + (size_t)(i * 64) * N_ + j * 64;
  int tid = threadIdx.x;
  if (d < 0) {
    for (int x = tid; x < 1024; x += 256) {
      int a = x >> 4, b4 = (x & 15) << 2;
      *(float4*)(out + (size_t)a * N_ + b4) = *(const float4*)(Ad + a * 64 + b4);
    }
  } else {
    __shared__ float ts[64][65];
    for (int x = tid; x < 1024; x += 256) {
      int r = x >> 4, c4 = (x & 15) << 2;
      float4 v = *(const float4*)(Ad + r * 64 + c4);
      ts[c4 + 0][r] = v.x; ts[c4 + 1][r] = v.y; ts[c4 + 2][r] = v.z; ts[c4 + 3][r] = v.w;
    }
    __syncthreads();
    for (int x = tid; x < 1024; x += 256) {
      int a = x >> 4, b4 = (x & 15) << 2;
      float4 v;
      v.x = ts[a][b4 + 0]; v.y = ts[a][b4 + 1]; v.z = ts[a][b4 + 2]; v.w = ts[a][b4 + 3];
      *(float4*)(out + (size_t)a * N_ + b4) = v;
    }
  }
}

// ---------------- prep: r[k][j][s] and cterm[k] ----------------
__global__ __launch_bounds__(256) void prepk(const float* __restrict__ A, const float* __restrict__ mu,
                                             float* __restrict__ rbuf, float* __restrict__ cterm) {
  int k = blockIdx.x;
  __shared__ float smu[64];
  __shared__ float sp[1024], sq[1024];
  int tid = threadIdx.x;
  if (tid < 64) smu[tid] = mu[k * 64 + tid];
  __syncthreads();
  for (int idx = tid; idx < 1024; idx += 256) {
    int d = idx >> 6, s = idx & 63;
    const float* Ad = A + ((size_t)(d * K_ + k) << 12);
    float ap = 0.f, aq = 0.f;
    for (int s2 = 0; s2 < 64; ++s2) {
      ap += Ad[s * 64 + s2] * smu[s2];
      aq += Ad[s2 * 64 + s] * smu[s2];
    }
    sp[idx] = ap; sq[idx] = aq;
  }
  __syncthreads();
  for (int idx = tid; idx < 1024; idx += 256) {
    int j = idx >> 6, s = idx & 63;
    float acc = 0.5f * (sp[s] + sq[s]);
    for (int d = 1; d < 16; ++d) {
      if (d <= 15 - j) acc += sp[d * 64 + s];
      if (d <= j)      acc += sq[d * 64 + s];
    }
    rbuf[k * 1024 + idx] = acc;
  }
  if (tid < 64) {
    float a = 16.f * sp[tid];
    for (int d = 1; d < 16; ++d) a += 2.f * (float)(16 - d) * sp[d * 64 + tid];
    a *= smu[tid];
    for (int off = 32; off; off >>= 1) a += __shfl_xor(a, off);
    if (tid == 0) cterm[k] = a;
  }
}

// ---------------- Q kernel: Qp[g][b][k] partial quadratic forms ----------------
__global__ __launch_bounds__(256) void qkern(const float* __restrict__ X, const float* __restrict__ A,
                                             float* __restrict__ Qp) {
  int g = blockIdx.x;
  int btile = blockIdx.y;
  __shared__ float Xs[4][1024];
  __shared__ float Cs[4][4096];
  int tid = threadIdx.x;
  int wave = tid >> 6, lane = tid & 63;
  for (int t = tid; t < 4096; t += 256) {
    int bb = t >> 10, e = t & 1023;
    Xs[bb][e] = X[(size_t)(btile * 4 + bb) * 1024 + e];
  }
  float regQ[4][8];
#pragma unroll
  for (int bb = 0; bb < 4; ++bb)
#pragma unroll
    for (int kk = 0; kk < 8; ++kk) regQ[bb][kk] = 0.f;

  int a0 = (tid >> 4) << 2;
  int v0 = (tid & 15) << 2;
  for (int dd = 0; dd < 4; ++dd) {
    int d = g + (dd << 2);
    __syncthreads();
    for (int bb = 0; bb < 4; ++bb) {
      float4 r0 = {0,0,0,0}, r1 = {0,0,0,0}, r2 = {0,0,0,0}, r3 = {0,0,0,0};
      for (int j = 0; j + d < 16; ++j) {
        const float4 xa = *(const float4*)&Xs[bb][j * 64 + a0];
        const float4 xv = *(const float4*)&Xs[bb][(j + d) * 64 + v0];
        r0.x += xa.x * xv.x; r0.y += xa.x * xv.y; r0.z += xa.x * xv.z; r0.w += xa.x * xv.w;
        r1.x += xa.y * xv.x; r1.y += xa.y * xv.y; r1.z += xa.y * xv.z; r1.w += xa.y * xv.w;
        r2.x += xa.z * xv.x; r2.y += xa.z * xv.y; r2.z += xa.z * xv.z; r2.w += xa.z * xv.w;
        r3.x += xa.w * xv.x; r3.y += xa.w * xv.y; r3.z += xa.w * xv.z; r3.w += xa.w * xv.w;
      }
      *(float4*)&Cs[bb][(a0 + 0) * 64 + v0] = r0;
      *(float4*)&Cs[bb][(a0 + 1) * 64 + v0] = r1;
      *(float4*)&Cs[bb][(a0 + 2) * 64 + v0] = r2;
      *(float4*)&Cs[bb][(a0 + 3) * 64 + v0] = r3;
    }
    __syncthreads();
    float w = (d == 0) ? 1.f : 2.f;
    for (int ch = 0; ch < 16; ++ch) {
      int e4 = (ch * 64 + lane) << 2;
      float4 cv[4];
#pragma unroll
      for (int bb = 0; bb < 4; ++bb) {
        float4 t4 = *(const float4*)&Cs[bb][e4];
        cv[bb].x = w * t4.x; cv[bb].y = w * t4.y; cv[bb].z = w * t4.z; cv[bb].w = w * t4.w;
      }
#pragma unroll
      for (int kk = 0; kk < 8; ++kk) {
        int k = wave + (kk << 2);
        const float4 av = *(const float4*)(A + (((size_t)(d * K_ + k)) << 12) + e4);
#pragma unroll
        for (int bb = 0; bb < 4; ++bb)
          regQ[bb][kk] += av.x * cv[bb].x + av.y * cv[bb].y + av.z * cv[bb].z + av.w * cv[bb].w;
      }
    }
  }
#pragma unroll
  for (int bb = 0; bb < 4; ++bb)
#pragma unroll
    for (int kk = 0; kk < 8; ++kk) {
      float v = regQ[bb][kk];
      for (int off = 32; off; off >>= 1) v += __shfl_xor(v, off);
      regQ[bb][kk] = v;
    }
  if (lane == 0) {
    int b = btile * 4;
#pragma unroll
    for (int bb = 0; bb < 4; ++bb)
#pragma unroll
      for (int kk = 0; kk < 8; ++kk)
        Qp[((size_t)(g * B_ + b + bb) << 5) + (wave + (kk << 2))] = regQ[bb][kk];
  }
}

// ---------------- LU panel (nb=32) v6: 512 threads x 2 register rows, 2 barriers/step ----
// Full-column partial pivoting (proven numerics). Thread t owns panel rows t (rA)
// and t+512 (rB). Per step: uniform redundant pivot select from LDS candidates,
// stage/swap via bufP/bufJ, rank-1 update + merged next-column scan. Fused TRSM
// epilogue writes U12 to Uws (same contract as Round 5).
__global__ __launch_bounds__(512) void panelk(float* __restrict__ M, int* __restrict__ rowmap,
                                              float* __restrict__ logdet, float* __restrict__ Uws,
                                              int j0) {
  int k = blockIdx.x;
  float* Mk = M + ((size_t)k << 20);
  int* rmk = rowmap + (k << 10);
  int m = N_ - j0;
  int t = threadIdx.x;
  int lane = t & 63, wid = t >> 6;   // 8 waves

  __shared__ float bufP[32];
  __shared__ float bufJ[32];
  __shared__ int origP, origJ;
  __shared__ float candv[8];
  __shared__ int candi[8];
  __shared__ float l11s[32 * 33];
  __shared__ int smapU[32];

  float rA[32], rB[32];
  int origA = -1, origB = -1;
  bool actA = (t < m);
  bool actB = (t + 512 < m);
  if (actA) {
    origA = rmk[j0 + t];
    const float* src = Mk + (size_t)origA * N_ + j0;
#pragma unroll
    for (int c4 = 0; c4 < 8; ++c4) *(float4*)&rA[c4 * 4] = *(const float4*)(src + c4 * 4);
  }
  if (actB) {
    origB = rmk[j0 + 512 + t];
    const float* src = Mk + (size_t)origB * N_ + j0;
#pragma unroll
    for (int c4 = 0; c4 < 8; ++c4) *(float4*)&rB[c4 * 4] = *(const float4*)(src + c4 * 4);
  }
  float ldacc = 0.f;

  // prologue: scan column 0
  {
    float bv = actA ? fabsf(rA[0]) : -1.f;
    int bi = t;
    if (actB) { float v = fabsf(rB[0]); if (v > bv) { bv = v; bi = t + 512; } }
#pragma unroll
    for (int off = 32; off; off >>= 1) {
      float ov = __shfl_xor(bv, off);
      int oi = __shfl_xor(bi, off);
      if (ov > bv) { bv = ov; bi = oi; }
    }
    if (lane == 0) { candv[wid] = bv; candi[wid] = bi; }
  }
  __syncthreads();

#pragma unroll
  for (int jj = 0; jj < 32; ++jj) {
    // ---- R2: all threads redundantly reduce the 8 wave candidates (uniform p) ----
    float cv = candv[0]; int p = candi[0];
#pragma unroll
    for (int w = 1; w < 8; ++w) { float v = candv[w]; if (v > cv) { cv = v; p = candi[w]; } }
    // stage pivot row; stage displaced row jj if swapping
    if (p < 512) {
      if (t == p) {
#pragma unroll
        for (int c4 = 0; c4 < 8; ++c4) *(float4*)&bufP[c4 * 4] = *(const float4*)&rA[c4 * 4];
        origP = origA;
      }
    } else if (t == p - 512) {
#pragma unroll
      for (int c4 = 0; c4 < 8; ++c4) *(float4*)&bufP[c4 * 4] = *(const float4*)&rB[c4 * 4];
      origP = origB;
    }
    if (p != jj && t == jj) {
#pragma unroll
      for (int c4 = 0; c4 < 8; ++c4) *(float4*)&bufJ[c4 * 4] = *(const float4*)&rA[c4 * 4];
      origJ = origA;
    }
    __syncthreads();
    // ---- R1': adopt swaps; broadcast pivot row; rank-1 update; merged next scan ----
    float pr[32];
#pragma unroll
    for (int c4 = 0; c4 < 8; ++c4) *(float4*)&pr[c4 * 4] = *(const float4*)&bufP[c4 * 4];
    if (p != jj) {
      if (t == jj) {
#pragma unroll
        for (int c = 0; c < 32; ++c) rA[c] = pr[c];
        origA = origP;
      }
      if (p < 512) {
        if (t == p) {
#pragma unroll
          for (int c4 = 0; c4 < 8; ++c4) *(float4*)&rA[c4 * 4] = *(const float4*)&bufJ[c4 * 4];
          origA = origJ;
        }
      } else if (t == p - 512) {
#pragma unroll
        for (int c4 = 0; c4 < 8; ++c4) *(float4*)&rB[c4 * 4] = *(const float4*)&bufJ[c4 * 4];
        origB = origJ;
      }
    }
    float pv = pr[jj];
    if (t == 0) ldacc += logf(fabsf(pv));
    float sinv = 1.0f / pv;
    if (actA && t > jj) {
      float mult = rA[jj] * sinv;
      rA[jj] = mult;
#pragma unroll
      for (int c = jj + 1; c < 32; ++c) rA[c] -= mult * pr[c];
    }
    if (actB) {
      float mult = rB[jj] * sinv;
      rB[jj] = mult;
#pragma unroll
      for (int c = jj + 1; c < 32; ++c) rB[c] -= mult * pr[c];
    }
    if (jj < 31) {
      float bv = (actA && t > jj) ? fabsf(rA[jj + 1]) : -1.f;
      int bi = t;
      if (actB) { float v = fabsf(rB[jj + 1]); if (v > bv) { bv = v; bi = t + 512; } }
#pragma unroll
      for (int off = 32; off; off >>= 1) {
        float ov = __shfl_xor(bv, off);
        int oi = __shfl_xor(bi, off);
        if (ov > bv) { bv = ov; bi = oi; }
      }
      if (lane == 0) { candv[wid] = bv; candi[wid] = bi; }
    }
    __syncthreads();
  }

  // ---- logdet ----
  if (t == 0) logdet[k] += ldacc;
  // ---- stage L11\U11 + pivoted-row origins for the TRSM epilogue ----
  if (t < 32) {
#pragma unroll
    for (int c = 0; c < 32; ++c) l11s[t * 33 + c] = rA[c];
    smapU[t] = origA;
  }
  // ---- export L/U panel (pivoted order, dense) + rowmap writeback ----
  if (actA) {
    float* dst = Mk + (size_t)(j0 + t) * N_ + j0;
#pragma unroll
    for (int c4 = 0; c4 < 8; ++c4) *(float4*)(dst + c4 * 4) = *(const float4*)&rA[c4 * 4];
    rmk[j0 + t] = origA;
  }
  if (actB) {
    float* dst = Mk + (size_t)(j0 + 512 + t) * N_ + j0;
#pragma unroll
    for (int c4 = 0; c4 < 8; ++c4) *(float4*)(dst + c4 * 4) = *(const float4*)&rB[c4 * 4];
    rmk[j0 + 512 + t] = origB;
  }
  __syncthreads();

  // ---- fused TRSM: U12 = L11^{-1} A12, one column per thread (2 strided passes) ----
  int mprime = m - 32;
  float* Uk = Uws + ((size_t)k << 15);
  for (int cx = t; cx < mprime; cx += 512) {
    int col = j0 + 32 + cx;
    float u[32];
#pragma unroll
    for (int rr = 0; rr < 32; ++rr) {
      float av = Mk[(size_t)smapU[rr] * N_ + col];
#pragma unroll
      for (int tt = 0; tt < 32; ++tt) { if (tt < rr) av -= l11s[rr * 33 + tt] * u[tt]; }
      u[rr] = av;
      Uk[(rr << 10) + col] = av;
    }
  }
}

// ---------------- trailing GEMM update, 128x128 C tile, C-early-load ----------------
__global__ __launch_bounds__(256) void updatek(float* __restrict__ M, const int* __restrict__ rowmap,
                                               const float* __restrict__ Uws, int j0) {
  int k = blockIdx.z;
  int mprime = N_ - j0 - 32;
  int r0 = blockIdx.y << 7;
  int c0 = blockIdx.x << 7;
  float* Mk = M + ((size_t)k << 20);
  const int* rmk = rowmap + (k << 10);
  __shared__ float LtT[32 * 132];
  __shared__ float Ut[32 * 132];
  __shared__ int rowL[128];
  int tid = threadIdx.x;

  if (tid < 128) rowL[tid] = (r0 + tid < mprime) ? rmk[j0 + 32 + r0 + tid] : -1;
  // stage L21^T from the dense panel export
  for (int x = tid; x < 1024; x += 256) {
    int rI = x >> 3, q = (x & 7) << 2;
    float4 v = {0.f, 0.f, 0.f, 0.f};
    if (r0 + rI < mprime) v = *(const float4*)(Mk + (size_t)(j0 + 32 + r0 + rI) * N_ + j0 + q);
    LtT[(q + 0) * 132 + rI] = v.x;
    LtT[(q + 1) * 132 + rI] = v.y;
    LtT[(q + 2) * 132 + rI] = v.z;
    LtT[(q + 3) * 132 + rI] = v.w;
  }
  // stage U12 tile from Uws (coalesced, already solved)
  {
    const float* Uk = Uws + ((size_t)k << 15) + j0 + 32 + c0;
    for (int x = tid; x < 1024; x += 256) {
      int rr = x >> 5, c4 = (x & 31) << 2;
      float4 v = {0.f, 0.f, 0.f, 0.f};
      if (c0 + c4 < mprime) v = *(const float4*)(Uk + (rr << 10) + c4);
      *(float4*)&Ut[rr * 132 + c4] = v;
    }
  }
  __syncthreads();

  int tx = tid & 15, ty = tid >> 4;
  int cc = c0 + (tx << 2);

  // ---- C tile early load (hides RMW read latency under the GEMM) ----
  float4 cur[2][2][4];
#pragma unroll
  for (int ri = 0; ri < 2; ++ri)
#pragma unroll
    for (int r = 0; r < 4; ++r) {
      int lr = (ty << 2) + r + (ri << 6);
      int pr = rowL[lr];
#pragma unroll
      for (int ci = 0; ci < 2; ++ci) {
        int lc = cc + (ci << 6);
        if (pr >= 0 && lc < mprime)
          cur[ri][ci][r] = *(const float4*)(Mk + (size_t)pr * N_ + j0 + 32 + lc);
        else
          cur[ri][ci][r] = make_float4(0.f, 0.f, 0.f, 0.f);
      }
    }

  // ---- GEMM: accumulate -= L21*U12 directly into the loaded C registers ----
#define FMS4(dst, s, b4) dst.x -= (s) * b4.x; dst.y -= (s) * b4.y; dst.z -= (s) * b4.z; dst.w -= (s) * b4.w;
#pragma unroll 8
  for (int tk = 0; tk < 32; ++tk) {
    float4 aL = *(const float4*)&LtT[tk * 132 + (ty << 2)];
    float4 aH = *(const float4*)&LtT[tk * 132 + (ty << 2) + 64];
    float4 bL = *(const float4*)&Ut[tk * 132 + (tx << 2)];
    float4 bH = *(const float4*)&Ut[tk * 132 + (tx << 2) + 64];
    FMS4(cur[0][0][0], aL.x, bL) FMS4(cur[0][0][1], aL.y, bL) FMS4(cur[0][0][2], aL.z, bL) FMS4(cur[0][0][3], aL.w, bL)
    FMS4(cur[0][1][0], aL.x, bH) FMS4(cur[0][1][1], aL.y, bH) FMS4(cur[0][1][2], aL.z, bH) FMS4(cur[0][1][3], aL.w, bH)
    FMS4(cur[1][0][0], aH.x, bL) FMS4(cur[1][0][1], aH.y, bL) FMS4(cur[1][0][2], aH.z, bL) FMS4(cur[1][0][3], aH.w, bL)
    FMS4(cur[1][1][0], aH.x, bH) FMS4(cur[1][1][1], aH.y, bH) FMS4(cur[1][1][2], aH.z, bH) FMS4(cur[1][1][3], aH.w, bH)
  }
#undef FMS4

  // ---- store back ----
#pragma unroll
  for (int ri = 0; ri < 2; ++ri)
#pragma unroll
    for (int r = 0; r < 4; ++r) {
      int lr = (ty << 2) + r + (ri << 6);
      int pr = rowL[lr];
      if (pr < 0) continue;
      float* rowp = Mk + (size_t)pr * N_ + j0 + 32;
#pragma unroll
      for (int ci = 0; ci < 2; ++ci) {
        int lc = cc + (ci << 6);
        if (lc < mprime) *(float4*)(rowp + lc) = cur[ri][ci][r];
      }
    }
}

// ---------------- final: cross term, lle, softmax ----------------
__global__ __launch_bounds__(256) void finalk(const float* __restrict__ X, const float* __restrict__ rbuf,
                                              const float* __restrict__ cterm, const float* __restrict__ logdet,
                                              const float* __restrict__ Qp, float* __restrict__ out) {
  int b = blockIdx.x;
  __shared__ float Xs[1024];
  __shared__ float lleS[32];
  int tid = threadIdx.x, wave = tid >> 6, lane = tid & 63;
  for (int i = tid; i < 1024; i += 256) Xs[i] = X[(size_t)b * 1024 + i];
  __syncthreads();
#pragma unroll
  for (int kk = 0; kk < 8; ++kk) {
    int k = wave + (kk << 2);
    const float* rk = rbuf + (size_t)k * 1024;
    float acc = 0.f;
#pragma unroll
    for (int ch = 0; ch < 4; ++ch) {
      int e4 = (ch * 64 + lane) << 2;
      const float4 rv = *(const float4*)(rk + e4);
      const float4 xv = *(const float4*)&Xs[e4];
      acc += rv.x * xv.x + rv.y * xv.y + rv.z * xv.z + rv.w * xv.w;
    }
    for (int off = 32; off; off >>= 1) acc += __shfl_xor(acc, off);
    if (lane == 0) {
      float Qv = 0.f;
#pragma unroll
      for (int g = 0; g < 4; ++g) Qv += Qp[((size_t)(g * B_ + b) << 5) + k];
      float P1 = Qv - 2.f * acc + cterm[k];
      lleS[k] = -0.5f * P1 + logdet[k];
    }
  }
  __syncthreads();
  if (wave == 0) {
    float v = lleS[lane & 31];
    float mx = v;
    for (int off = 16; off; off >>= 1) mx = fmaxf(mx, __shfl_xor(mx, off));
    float e = expf(v - mx);
    float s = e;
    for (int off = 16; off; off >>= 1) s += __shfl_xor(s, off);
    if (lane < 32) out[b * 32 + lane] = e / s;
  }
}

extern "C" void kernel_launch(void* const* d_in, const int* in_sizes, int n_in,
                              void* d_out, int out_size, void* d_ws, size_t ws_size,
                              hipStream_t stream) {
  const float* X  = (const float*)d_in[0];
  const float* mu = (const float*)d_in[1];
  const float* A  = (const float*)d_in[2];
  float* out = (float*)d_out;
  float* ws  = (float*)d_ws;

  if (ws_size < 138936576ull) {   // 128 MB M + maps + 4 MB U stripe
    hipMemsetAsync(d_out, 0, (size_t)out_size * sizeof(float), stream);
    return;
  }

  float* M      = ws;                        // 33554432 floats (128 MB)
  int*   rowmap = (int*)(ws + 33554432);     // 32768 ints
  float* logdet = ws + 33587200;             // 32
  float* rbuf   = ws + 33587232;             // 32768
  float* cterm  = ws + 33620000;             // 32
  float* Qp     = ws + 33620032;             // 65536
  float* Uws    = ws + 33685568;             // 32*32*1024 = 1048576 floats (4 MB)

  initk<<<dim3(128), dim3(256), 0, stream>>>(rowmap, logdet);
  buildM<<<dim3(16, 16, 32), dim3(256), 0, stream>>>(A, M);
  prepk<<<dim3(32), dim3(256), 0, stream>>>(A, mu, rbuf, cterm);
  qkern<<<dim3(4, 128), dim3(256), 0, stream>>>(X, A, Qp);

  for (int s = 0; s < 32; ++s) {
    int j0 = s * 32;
    panelk<<<dim3(32), dim3(512), 0, stream>>>(M, rowmap, logdet, Uws, j0);
    int mprime = N_ - j0 - 32;
    if (mprime > 0) {
      int mt = (mprime + 127) >> 7;
      updatek<<<dim3(mt, mt, 32), dim3(256), 0, stream>>>(M, rowmap, Uws, j0);
    }
  }

  finalk<<<dim3(512), dim3(256), 0, stream>>>(X, rbuf, cterm, logdet, Qp, out);
}

// Round 8
// 4067.985 us; speedup vs baseline: 1.9462x; 1.9462x over previous
//
#include <hip/hip_runtime.h>
#include <math.h>

static constexpr int B_ = 512;
static constexpr int T_ = 16;
static constexpr int S_ = 64;
static constexpr int K_ = 32;
static constexpr int N_ = 1024;   // T_*S_

// ---------------- init: rowmap identity + logdet zero ----------------
__global__ void initk(int* __restrict__ rowmap, float* __restrict__ logdet) {
  int idx = blockIdx.x * 256 + threadIdx.x;
  if (idx < K_ * N_) rowmap[idx] = idx & (N_ - 1);
  if (idx < K_) logdet[idx] = 0.f;
}

// ---------------- build block-Toeplitz M[k][row][col], LDS-transpose version ----
__global__ __launch_bounds__(256) void buildM(const float* __restrict__ A, float* __restrict__ M) {
  int k = blockIdx.z, i = blockIdx.y, j = blockIdx.x;
  int d = i - j;
  int ad = d >= 0 ? d : -d;
  const float* Ad = A + ((size_t)(ad * K_ + k) << 12);
  float* out = M + ((size_t)k << 20) + (size_t)(i * 64) * N_ + j * 64;
  int tid = threadIdx.x;
  if (d < 0) {
    for (int x = tid; x < 1024; x += 256) {
      int a = x >> 4, b4 = (x & 15) << 2;
      *(float4*)(out + (size_t)a * N_ + b4) = *(const float4*)(Ad + a * 64 + b4);
    }
  } else {
    __shared__ float ts[64][65];
    for (int x = tid; x < 1024; x += 256) {
      int r = x >> 4, c4 = (x & 15) << 2;
      float4 v = *(const float4*)(Ad + r * 64 + c4);
      ts[c4 + 0][r] = v.x; ts[c4 + 1][r] = v.y; ts[c4 + 2][r] = v.z; ts[c4 + 3][r] = v.w;
    }
    __syncthreads();
    for (int x = tid; x < 1024; x += 256) {
      int a = x >> 4, b4 = (x & 15) << 2;
      float4 v;
      v.x = ts[a][b4 + 0]; v.y = ts[a][b4 + 1]; v.z = ts[a][b4 + 2]; v.w = ts[a][b4 + 3];
      *(float4*)(out + (size_t)a * N_ + b4) = v;
    }
  }
}

// ---------------- prep: r[k][j][s] and cterm[k] ----------------
__global__ __launch_bounds__(256) void prepk(const float* __restrict__ A, const float* __restrict__ mu,
                                             float* __restrict__ rbuf, float* __restrict__ cterm) {
  int k = blockIdx.x;
  __shared__ float smu[64];
  __shared__ float sp[1024], sq[1024];
  int tid = threadIdx.x;
  if (tid < 64) smu[tid] = mu[k * 64 + tid];
  __syncthreads();
  for (int idx = tid; idx < 1024; idx += 256) {
    int d = idx >> 6, s = idx & 63;
    const float* Ad = A + ((size_t)(d * K_ + k) << 12);
    float ap = 0.f, aq = 0.f;
    for (int s2 = 0; s2 < 64; ++s2) {
      ap += Ad[s * 64 + s2] * smu[s2];
      aq += Ad[s2 * 64 + s] * smu[s2];
    }
    sp[idx] = ap; sq[idx] = aq;
  }
  __syncthreads();
  for (int idx = tid; idx < 1024; idx += 256) {
    int j = idx >> 6, s = idx & 63;
    float acc = 0.5f * (sp[s] + sq[s]);
    for (int d = 1; d < 16; ++d) {
      if (d <= 15 - j) acc += sp[d * 64 + s];
      if (d <= j)      acc += sq[d * 64 + s];
    }
    rbuf[k * 1024 + idx] = acc;
  }
  if (tid < 64) {
    float a = 16.f * sp[tid];
    for (int d = 1; d < 16; ++d) a += 2.f * (float)(16 - d) * sp[d * 64 + tid];
    a *= smu[tid];
    for (int off = 32; off; off >>= 1) a += __shfl_xor(a, off);
    if (tid == 0) cterm[k] = a;
  }
}

// ---------------- Q kernel: Qp[g][b][k] partial quadratic forms ----------------
__global__ __launch_bounds__(256) void qkern(const float* __restrict__ X, const float* __restrict__ A,
                                             float* __restrict__ Qp) {
  int g = blockIdx.x;
  int btile = blockIdx.y;
  __shared__ float Xs[4][1024];
  __shared__ float Cs[4][4096];
  int tid = threadIdx.x;
  int wave = tid >> 6, lane = tid & 63;
  for (int t = tid; t < 4096; t += 256) {
    int bb = t >> 10, e = t & 1023;
    Xs[bb][e] = X[(size_t)(btile * 4 + bb) * 1024 + e];
  }
  float regQ[4][8];
#pragma unroll
  for (int bb = 0; bb < 4; ++bb)
#pragma unroll
    for (int kk = 0; kk < 8; ++kk) regQ[bb][kk] = 0.f;

  int a0 = (tid >> 4) << 2;
  int v0 = (tid & 15) << 2;
  for (int dd = 0; dd < 4; ++dd) {
    int d = g + (dd << 2);
    __syncthreads();
    for (int bb = 0; bb < 4; ++bb) {
      float4 r0 = {0,0,0,0}, r1 = {0,0,0,0}, r2 = {0,0,0,0}, r3 = {0,0,0,0};
      for (int j = 0; j + d < 16; ++j) {
        const float4 xa = *(const float4*)&Xs[bb][j * 64 + a0];
        const float4 xv = *(const float4*)&Xs[bb][(j + d) * 64 + v0];
        r0.x += xa.x * xv.x; r0.y += xa.x * xv.y; r0.z += xa.x * xv.z; r0.w += xa.x * xv.w;
        r1.x += xa.y * xv.x; r1.y += xa.y * xv.y; r1.z += xa.y * xv.z; r1.w += xa.y * xv.w;
        r2.x += xa.z * xv.x; r2.y += xa.z * xv.y; r2.z += xa.z * xv.z; r2.w += xa.z * xv.w;
        r3.x += xa.w * xv.x; r3.y += xa.w * xv.y; r3.z += xa.w * xv.z; r3.w += xa.w * xv.w;
      }
      *(float4*)&Cs[bb][(a0 + 0) * 64 + v0] = r0;
      *(float4*)&Cs[bb][(a0 + 1) * 64 + v0] = r1;
      *(float4*)&Cs[bb][(a0 + 2) * 64 + v0] = r2;
      *(float4*)&Cs[bb][(a0 + 3) * 64 + v0] = r3;
    }
    __syncthreads();
    float w = (d == 0) ? 1.f : 2.f;
    for (int ch = 0; ch < 16; ++ch) {
      int e4 = (ch * 64 + lane) << 2;
      float4 cv[4];
#pragma unroll
      for (int bb = 0; bb < 4; ++bb) {
        float4 t4 = *(const float4*)&Cs[bb][e4];
        cv[bb].x = w * t4.x; cv[bb].y = w * t4.y; cv[bb].z = w * t4.z; cv[bb].w = w * t4.w;
      }
#pragma unroll
      for (int kk = 0; kk < 8; ++kk) {
        int k = wave + (kk << 2);
        const float4 av = *(const float4*)(A + (((size_t)(d * K_ + k)) << 12) + e4);
#pragma unroll
        for (int bb = 0; bb < 4; ++bb)
          regQ[bb][kk] += av.x * cv[bb].x + av.y * cv[bb].y + av.z * cv[bb].z + av.w * cv[bb].w;
      }
    }
  }
#pragma unroll
  for (int bb = 0; bb < 4; ++bb)
#pragma unroll
    for (int kk = 0; kk < 8; ++kk) {
      float v = regQ[bb][kk];
      for (int off = 32; off; off >>= 1) v += __shfl_xor(v, off);
      regQ[bb][kk] = v;
    }
  if (lane == 0) {
    int b = btile * 4;
#pragma unroll
    for (int bb = 0; bb < 4; ++bb)
#pragma unroll
      for (int kk = 0; kk < 8; ++kk)
        Qp[((size_t)(g * B_ + b + bb) << 5) + (wave + (kk << 2))] = regQ[bb][kk];
  }
}

// ---------------- panel step (compile-time JJ): full-column partial pivoting ----------------
// 256 threads; thread t owns rows t, t+256, t+512, t+768 in r0..r3 (registers).
// Phase A (post-barrier): all threads redundantly reduce the 4 wave candidates,
// stage pivot row to bufP (and displaced row JJ to bufJ). Phase B: adopt swaps,
// rank-1 update with FMA operands read from LDS bufP, merged next-column scan.
template<int JJ>
__device__ __forceinline__ void panel_step(
    float (&r0)[32], float (&r1)[32], float (&r2)[32], float (&r3)[32],
    int& o0, int& o1, int& o2, int& o3,
    bool a0, bool a1, bool a2, bool a3,
    int t, int lane, int wid,
    float* bufP, float* bufJ, int* origP, int* origJ,
    float* candv, int* candi, float& ldacc) {
  // ---- phase A: uniform pivot select ----
  float cv = candv[0]; int p = candi[0];
#pragma unroll
  for (int w = 1; w < 4; ++w) { float v = candv[w]; if (v > cv) { cv = v; p = candi[w]; } }
  int pt = p & 255, ps = p >> 8;
  if (t == pt) {
    if (ps == 0) {
#pragma unroll
      for (int c = 0; c < 32; ++c) bufP[c] = r0[c];
      *origP = o0;
    } else if (ps == 1) {
#pragma unroll
      for (int c = 0; c < 32; ++c) bufP[c] = r1[c];
      *origP = o1;
    } else if (ps == 2) {
#pragma unroll
      for (int c = 0; c < 32; ++c) bufP[c] = r2[c];
      *origP = o2;
    } else {
#pragma unroll
      for (int c = 0; c < 32; ++c) bufP[c] = r3[c];
      *origP = o3;
    }
  }
  if (p != JJ && t == JJ) {   // row JJ is always slot 0 (JJ < 32)
#pragma unroll
    for (int c = 0; c < 32; ++c) bufJ[c] = r0[c];
    *origJ = o0;
  }
  __syncthreads();
  // ---- phase B: adopt swaps ----
  if (p != JJ) {
    if (t == JJ) {
#pragma unroll
      for (int c = 0; c < 32; ++c) r0[c] = bufP[c];
      o0 = *origP;
    }
    if (t == pt) {
      if (ps == 0) {
        if (pt != JJ) {   // pt==JJ can't happen with ps==0 unless p==JJ
#pragma unroll
          for (int c = 0; c < 32; ++c) r0[c] = bufJ[c];
          o0 = *origJ;
        }
      } else if (ps == 1) {
#pragma unroll
        for (int c = 0; c < 32; ++c) r1[c] = bufJ[c];
        o1 = *origJ;
      } else if (ps == 2) {
#pragma unroll
        for (int c = 0; c < 32; ++c) r2[c] = bufJ[c];
        o2 = *origJ;
      } else {
#pragma unroll
        for (int c = 0; c < 32; ++c) r3[c] = bufJ[c];
        o3 = *origJ;
      }
    }
  }
  float pv = bufP[JJ];
  if (t == 0) ldacc += logf(fabsf(pv));
  float sinv = 1.0f / pv;
  // ---- rank-1 update + merged scan of column JJ+1 ----
  float bv = -1.f; int bi = t;
  if (a0 && t > JJ) {
    float mult = r0[JJ] * sinv;
    r0[JJ] = mult;
#pragma unroll
    for (int c = JJ + 1; c < 32; ++c) r0[c] -= mult * bufP[c];
    if (JJ < 31) { bv = fabsf(r0[JJ + 1]); }
  }
  if (a1) {
    float mult = r1[JJ] * sinv;
    r1[JJ] = mult;
#pragma unroll
    for (int c = JJ + 1; c < 32; ++c) r1[c] -= mult * bufP[c];
    if (JJ < 31) { float v = fabsf(r1[JJ + 1]); if (v > bv) { bv = v; bi = t + 256; } }
  }
  if (a2) {
    float mult = r2[JJ] * sinv;
    r2[JJ] = mult;
#pragma unroll
    for (int c = JJ + 1; c < 32; ++c) r2[c] -= mult * bufP[c];
    if (JJ < 31) { float v = fabsf(r2[JJ + 1]); if (v > bv) { bv = v; bi = t + 512; } }
  }
  if (a3) {
    float mult = r3[JJ] * sinv;
    r3[JJ] = mult;
#pragma unroll
    for (int c = JJ + 1; c < 32; ++c) r3[c] -= mult * bufP[c];
    if (JJ < 31) { float v = fabsf(r3[JJ + 1]); if (v > bv) { bv = v; bi = t + 768; } }
  }
  if (JJ < 31) {
#pragma unroll
    for (int off = 32; off; off >>= 1) {
      float ov = __shfl_xor(bv, off);
      int oi = __shfl_xor(bi, off);
      if (ov > bv) { bv = ov; bi = oi; }
    }
    if (lane == 0) { candv[wid] = bv; candi[wid] = bi; }
  }
  __syncthreads();
}

// ---------------- LU panel (nb=32) v7: 256 threads x 4 register rows ----------------
__global__ __launch_bounds__(256, 1) void panelk(float* __restrict__ M, int* __restrict__ rowmap,
                                                 float* __restrict__ logdet, float* __restrict__ Uws,
                                                 int j0) {
  int k = blockIdx.x;
  float* Mk = M + ((size_t)k << 20);
  int* rmk = rowmap + (k << 10);
  int m = N_ - j0;
  int t = threadIdx.x;
  int lane = t & 63, wid = t >> 6;

  __shared__ float bufP[32];
  __shared__ float bufJ[32];
  __shared__ int origP, origJ;
  __shared__ float candv[4];
  __shared__ int candi[4];
  __shared__ float l11s[32 * 33];
  __shared__ int smapU[32];

  float r0[32], r1[32], r2[32], r3[32];
  int o0 = -1, o1 = -1, o2 = -1, o3 = -1;
  bool a0 = (t < m), a1 = (t + 256 < m), a2 = (t + 512 < m), a3 = (t + 768 < m);
  if (a0) {
    o0 = rmk[j0 + t];
    const float* src = Mk + (size_t)o0 * N_ + j0;
#pragma unroll
    for (int c4 = 0; c4 < 8; ++c4) *(float4*)&r0[c4 * 4] = *(const float4*)(src + c4 * 4);
  }
  if (a1) {
    o1 = rmk[j0 + 256 + t];
    const float* src = Mk + (size_t)o1 * N_ + j0;
#pragma unroll
    for (int c4 = 0; c4 < 8; ++c4) *(float4*)&r1[c4 * 4] = *(const float4*)(src + c4 * 4);
  }
  if (a2) {
    o2 = rmk[j0 + 512 + t];
    const float* src = Mk + (size_t)o2 * N_ + j0;
#pragma unroll
    for (int c4 = 0; c4 < 8; ++c4) *(float4*)&r2[c4 * 4] = *(const float4*)(src + c4 * 4);
  }
  if (a3) {
    o3 = rmk[j0 + 768 + t];
    const float* src = Mk + (size_t)o3 * N_ + j0;
#pragma unroll
    for (int c4 = 0; c4 < 8; ++c4) *(float4*)&r3[c4 * 4] = *(const float4*)(src + c4 * 4);
  }
  float ldacc = 0.f;

  // prologue: scan column 0
  {
    float bv = a0 ? fabsf(r0[0]) : -1.f;
    int bi = t;
    if (a1) { float v = fabsf(r1[0]); if (v > bv) { bv = v; bi = t + 256; } }
    if (a2) { float v = fabsf(r2[0]); if (v > bv) { bv = v; bi = t + 512; } }
    if (a3) { float v = fabsf(r3[0]); if (v > bv) { bv = v; bi = t + 768; } }
#pragma unroll
    for (int off = 32; off; off >>= 1) {
      float ov = __shfl_xor(bv, off);
      int oi = __shfl_xor(bi, off);
      if (ov > bv) { bv = ov; bi = oi; }
    }
    if (lane == 0) { candv[wid] = bv; candi[wid] = bi; }
  }
  __syncthreads();

#define PSTEP(JJ) panel_step<JJ>(r0, r1, r2, r3, o0, o1, o2, o3, a0, a1, a2, a3, \
                                 t, lane, wid, bufP, bufJ, &origP, &origJ, candv, candi, ldacc);
  PSTEP(0)  PSTEP(1)  PSTEP(2)  PSTEP(3)  PSTEP(4)  PSTEP(5)  PSTEP(6)  PSTEP(7)
  PSTEP(8)  PSTEP(9)  PSTEP(10) PSTEP(11) PSTEP(12) PSTEP(13) PSTEP(14) PSTEP(15)
  PSTEP(16) PSTEP(17) PSTEP(18) PSTEP(19) PSTEP(20) PSTEP(21) PSTEP(22) PSTEP(23)
  PSTEP(24) PSTEP(25) PSTEP(26) PSTEP(27) PSTEP(28) PSTEP(29) PSTEP(30) PSTEP(31)
#undef PSTEP

  // ---- logdet ----
  if (t == 0) logdet[k] += ldacc;
  // ---- stage L11\U11 + pivoted-row origins for the TRSM epilogue (rows 0..31 = slot 0) ----
  if (t < 32) {
#pragma unroll
    for (int c = 0; c < 32; ++c) l11s[t * 33 + c] = r0[c];
    smapU[t] = o0;
  }
  // ---- export L/U panel (pivoted order, dense) + rowmap writeback ----
  if (a0) {
    float* dst = Mk + (size_t)(j0 + t) * N_ + j0;
#pragma unroll
    for (int c4 = 0; c4 < 8; ++c4) *(float4*)(dst + c4 * 4) = *(const float4*)&r0[c4 * 4];
    rmk[j0 + t] = o0;
  }
  if (a1) {
    float* dst = Mk + (size_t)(j0 + 256 + t) * N_ + j0;
#pragma unroll
    for (int c4 = 0; c4 < 8; ++c4) *(float4*)(dst + c4 * 4) = *(const float4*)&r1[c4 * 4];
    rmk[j0 + 256 + t] = o1;
  }
  if (a2) {
    float* dst = Mk + (size_t)(j0 + 512 + t) * N_ + j0;
#pragma unroll
    for (int c4 = 0; c4 < 8; ++c4) *(float4*)(dst + c4 * 4) = *(const float4*)&r2[c4 * 4];
    rmk[j0 + 512 + t] = o2;
  }
  if (a3) {
    float* dst = Mk + (size_t)(j0 + 768 + t) * N_ + j0;
#pragma unroll
    for (int c4 = 0; c4 < 8; ++c4) *(float4*)(dst + c4 * 4) = *(const float4*)&r3[c4 * 4];
    rmk[j0 + 768 + t] = o3;
  }
  __syncthreads();

  // ---- fused TRSM: U12 = L11^{-1} A12, one column per thread, strided ----
  int mprime = m - 32;
  float* Uk = Uws + ((size_t)k << 15);
  for (int cx = t; cx < mprime; cx += 256) {
    int col = j0 + 32 + cx;
    float u[32];
#pragma unroll
    for (int rr = 0; rr < 32; ++rr) {
      float av = Mk[(size_t)smapU[rr] * N_ + col];
#pragma unroll
      for (int tt = 0; tt < 32; ++tt) { if (tt < rr) av -= l11s[rr * 33 + tt] * u[tt]; }
      u[rr] = av;
      Uk[(rr << 10) + col] = av;
    }
  }
}

// ---------------- trailing GEMM update, 128x128 C tile, C-early-load ----------------
__global__ __launch_bounds__(256) void updatek(float* __restrict__ M, const int* __restrict__ rowmap,
                                               const float* __restrict__ Uws, int j0) {
  int k = blockIdx.z;
  int mprime = N_ - j0 - 32;
  int r0 = blockIdx.y << 7;
  int c0 = blockIdx.x << 7;
  float* Mk = M + ((size_t)k << 20);
  const int* rmk = rowmap + (k << 10);
  __shared__ float LtT[32 * 132];
  __shared__ float Ut[32 * 132];
  __shared__ int rowL[128];
  int tid = threadIdx.x;

  if (tid < 128) rowL[tid] = (r0 + tid < mprime) ? rmk[j0 + 32 + r0 + tid] : -1;
  for (int x = tid; x < 1024; x += 256) {
    int rI = x >> 3, q = (x & 7) << 2;
    float4 v = {0.f, 0.f, 0.f, 0.f};
    if (r0 + rI < mprime) v = *(const float4*)(Mk + (size_t)(j0 + 32 + r0 + rI) * N_ + j0 + q);
    LtT[(q + 0) * 132 + rI] = v.x;
    LtT[(q + 1) * 132 + rI] = v.y;
    LtT[(q + 2) * 132 + rI] = v.z;
    LtT[(q + 3) * 132 + rI] = v.w;
  }
  {
    const float* Uk = Uws + ((size_t)k << 15) + j0 + 32 + c0;
    for (int x = tid; x < 1024; x += 256) {
      int rr = x >> 5, c4 = (x & 31) << 2;
      float4 v = {0.f, 0.f, 0.f, 0.f};
      if (c0 + c4 < mprime) v = *(const float4*)(Uk + (rr << 10) + c4);
      *(float4*)&Ut[rr * 132 + c4] = v;
    }
  }
  __syncthreads();

  int tx = tid & 15, ty = tid >> 4;
  int cc = c0 + (tx << 2);

  float4 cur[2][2][4];
#pragma unroll
  for (int ri = 0; ri < 2; ++ri)
#pragma unroll
    for (int r = 0; r < 4; ++r) {
      int lr = (ty << 2) + r + (ri << 6);
      int pr = rowL[lr];
#pragma unroll
      for (int ci = 0; ci < 2; ++ci) {
        int lc = cc + (ci << 6);
        if (pr >= 0 && lc < mprime)
          cur[ri][ci][r] = *(const float4*)(Mk + (size_t)pr * N_ + j0 + 32 + lc);
        else
          cur[ri][ci][r] = make_float4(0.f, 0.f, 0.f, 0.f);
      }
    }

#define FMS4(dst, s, b4) dst.x -= (s) * b4.x; dst.y -= (s) * b4.y; dst.z -= (s) * b4.z; dst.w -= (s) * b4.w;
#pragma unroll 8
  for (int tk = 0; tk < 32; ++tk) {
    float4 aL = *(const float4*)&LtT[tk * 132 + (ty << 2)];
    float4 aH = *(const float4*)&LtT[tk * 132 + (ty << 2) + 64];
    float4 bL = *(const float4*)&Ut[tk * 132 + (tx << 2)];
    float4 bH = *(const float4*)&Ut[tk * 132 + (tx << 2) + 64];
    FMS4(cur[0][0][0], aL.x, bL) FMS4(cur[0][0][1], aL.y, bL) FMS4(cur[0][0][2], aL.z, bL) FMS4(cur[0][0][3], aL.w, bL)
    FMS4(cur[0][1][0], aL.x, bH) FMS4(cur[0][1][1], aL.y, bH) FMS4(cur[0][1][2], aL.z, bH) FMS4(cur[0][1][3], aL.w, bH)
    FMS4(cur[1][0][0], aH.x, bL) FMS4(cur[1][0][1], aH.y, bL) FMS4(cur[1][0][2], aH.z, bL) FMS4(cur[1][0][3], aH.w, bL)
    FMS4(cur[1][1][0], aH.x, bH) FMS4(cur[1][1][1], aH.y, bH) FMS4(cur[1][1][2], aH.z, bH) FMS4(cur[1][1][3], aH.w, bH)
  }
#undef FMS4

#pragma unroll
  for (int ri = 0; ri < 2; ++ri)
#pragma unroll
    for (int r = 0; r < 4; ++r) {
      int lr = (ty << 2) + r + (ri << 6);
      int pr = rowL[lr];
      if (pr < 0) continue;
      float* rowp = Mk + (size_t)pr * N_ + j0 + 32;
#pragma unroll
      for (int ci = 0; ci < 2; ++ci) {
        int lc = cc + (ci << 6);
        if (lc < mprime) *(float4*)(rowp + lc) = cur[ri][ci][r];
      }
    }
}

// ---------------- final: cross term, lle, softmax ----------------
__global__ __launch_bounds__(256) void finalk(const float* __restrict__ X, const float* __restrict__ rbuf,
                                              const float* __restrict__ cterm, const float* __restrict__ logdet,
                                              const float* __restrict__ Qp, float* __restrict__ out) {
  int b = blockIdx.x;
  __shared__ float Xs[1024];
  __shared__ float lleS[32];
  int tid = threadIdx.x, wave = tid >> 6, lane = tid & 63;
  for (int i = tid; i < 1024; i += 256) Xs[i] = X[(size_t)b * 1024 + i];
  __syncthreads();
#pragma unroll
  for (int kk = 0; kk < 8; ++kk) {
    int k = wave + (kk << 2);
    const float* rk = rbuf + (size_t)k * 1024;
    float acc = 0.f;
#pragma unroll
    for (int ch = 0; ch < 4; ++ch) {
      int e4 = (ch * 64 + lane) << 2;
      const float4 rv = *(const float4*)(rk + e4);
      const float4 xv = *(const float4*)&Xs[e4];
      acc += rv.x * xv.x + rv.y * xv.y + rv.z * xv.z + rv.w * xv.w;
    }
    for (int off = 32; off; off >>= 1) acc += __shfl_xor(acc, off);
    if (lane == 0) {
      float Qv = 0.f;
#pragma unroll
      for (int g = 0; g < 4; ++g) Qv += Qp[((size_t)(g * B_ + b) << 5) + k];
      float P1 = Qv - 2.f * acc + cterm[k];
      lleS[k] = -0.5f * P1 + logdet[k];
    }
  }
  __syncthreads();
  if (wave == 0) {
    float v = lleS[lane & 31];
    float mx = v;
    for (int off = 16; off; off >>= 1) mx = fmaxf(mx, __shfl_xor(mx, off));
    float e = expf(v - mx);
    float s = e;
    for (int off = 16; off; off >>= 1) s += __shfl_xor(s, off);
    if (lane < 32) out[b * 32 + lane] = e / s;
  }
}

extern "C" void kernel_launch(void* const* d_in, const int* in_sizes, int n_in,
                              void* d_out, int out_size, void* d_ws, size_t ws_size,
                              hipStream_t stream) {
  const float* X  = (const float*)d_in[0];
  const float* mu = (const float*)d_in[1];
  const float* A  = (const float*)d_in[2];
  float* out = (float*)d_out;
  float* ws  = (float*)d_ws;

  if (ws_size < 138936576ull) {   // 128 MB M + maps + 4 MB U stripe
    hipMemsetAsync(d_out, 0, (size_t)out_size * sizeof(float), stream);
    return;
  }

  float* M      = ws;                        // 33554432 floats (128 MB)
  int*   rowmap = (int*)(ws + 33554432);     // 32768 ints
  float* logdet = ws + 33587200;             // 32
  float* rbuf   = ws + 33587232;             // 32768
  float* cterm  = ws + 33620000;             // 32
  float* Qp     = ws + 33620032;             // 65536
  float* Uws    = ws + 33685568;             // 32*32*1024 = 1048576 floats (4 MB)

  initk<<<dim3(128), dim3(256), 0, stream>>>(rowmap, logdet);
  buildM<<<dim3(16, 16, 32), dim3(256), 0, stream>>>(A, M);
  prepk<<<dim3(32), dim3(256), 0, stream>>>(A, mu, rbuf, cterm);
  qkern<<<dim3(4, 128), dim3(256), 0, stream>>>(X, A, Qp);

  for (int s = 0; s < 32; ++s) {
    int j0 = s * 32;
    panelk<<<dim3(32), dim3(256), 0, stream>>>(M, rowmap, logdet, Uws, j0);
    int mprime = N_ - j0 - 32;
    if (mprime > 0) {
      int mt = (mprime + 127) >> 7;
      updatek<<<dim3(mt, mt, 32), dim3(256), 0, stream>>>(M, rowmap, Uws, j0);
    }
  }

  finalk<<<dim3(512), dim3(256), 0, stream>>>(X, rbuf, cterm, logdet, Qp, out);
}

// Round 9
// 3271.614 us; speedup vs baseline: 2.4199x; 1.2434x over previous
//
#include <hip/hip_runtime.h>
#include <math.h>

static constexpr int B_ = 512;
static constexpr int T_ = 16;
static constexpr int S_ = 64;
static constexpr int K_ = 32;
static constexpr int N_ = 1024;   // T_*S_

// ---------------- init: rowmap identity + logdet zero ----------------
__global__ void initk(int* __restrict__ rowmap, float* __restrict__ logdet) {
  int idx = blockIdx.x * 256 + threadIdx.x;
  if (idx < K_ * N_) rowmap[idx] = idx & (N_ - 1);
  if (idx < K_) logdet[idx] = 0.f;
}

// ---------------- build block-Toeplitz M[k][row][col], LDS-transpose version ----
__global__ __launch_bounds__(256) void buildM(const float* __restrict__ A, float* __restrict__ M) {
  int k = blockIdx.z, i = blockIdx.y, j = blockIdx.x;
  int d = i - j;
  int ad = d >= 0 ? d : -d;
  const float* Ad = A + ((size_t)(ad * K_ + k) << 12);
  float* out = M + ((size_t)k << 20) + (size_t)(i * 64) * N_ + j * 64;
  int tid = threadIdx.x;
  if (d < 0) {
    for (int x = tid; x < 1024; x += 256) {
      int a = x >> 4, b4 = (x & 15) << 2;
      *(float4*)(out + (size_t)a * N_ + b4) = *(const float4*)(Ad + a * 64 + b4);
    }
  } else {
    __shared__ float ts[64][65];
    for (int x = tid; x < 1024; x += 256) {
      int r = x >> 4, c4 = (x & 15) << 2;
      float4 v = *(const float4*)(Ad + r * 64 + c4);
      ts[c4 + 0][r] = v.x; ts[c4 + 1][r] = v.y; ts[c4 + 2][r] = v.z; ts[c4 + 3][r] = v.w;
    }
    __syncthreads();
    for (int x = tid; x < 1024; x += 256) {
      int a = x >> 4, b4 = (x & 15) << 2;
      float4 v;
      v.x = ts[a][b4 + 0]; v.y = ts[a][b4 + 1]; v.z = ts[a][b4 + 2]; v.w = ts[a][b4 + 3];
      *(float4*)(out + (size_t)a * N_ + b4) = v;
    }
  }
}

// ---------------- prep: r[k][j][s] and cterm[k] ----------------
__global__ __launch_bounds__(256) void prepk(const float* __restrict__ A, const float* __restrict__ mu,
                                             float* __restrict__ rbuf, float* __restrict__ cterm) {
  int k = blockIdx.x;
  __shared__ float smu[64];
  __shared__ float sp[1024], sq[1024];
  int tid = threadIdx.x;
  if (tid < 64) smu[tid] = mu[k * 64 + tid];
  __syncthreads();
  for (int idx = tid; idx < 1024; idx += 256) {
    int d = idx >> 6, s = idx & 63;
    const float* Ad = A + ((size_t)(d * K_ + k) << 12);
    float ap = 0.f, aq = 0.f;
    for (int s2 = 0; s2 < 64; ++s2) {
      ap += Ad[s * 64 + s2] * smu[s2];
      aq += Ad[s2 * 64 + s] * smu[s2];
    }
    sp[idx] = ap; sq[idx] = aq;
  }
  __syncthreads();
  for (int idx = tid; idx < 1024; idx += 256) {
    int j = idx >> 6, s = idx & 63;
    float acc = 0.5f * (sp[s] + sq[s]);
    for (int d = 1; d < 16; ++d) {
      if (d <= 15 - j) acc += sp[d * 64 + s];
      if (d <= j)      acc += sq[d * 64 + s];
    }
    rbuf[k * 1024 + idx] = acc;
  }
  if (tid < 64) {
    float a = 16.f * sp[tid];
    for (int d = 1; d < 16; ++d) a += 2.f * (float)(16 - d) * sp[d * 64 + tid];
    a *= smu[tid];
    for (int off = 32; off; off >>= 1) a += __shfl_xor(a, off);
    if (tid == 0) cterm[k] = a;
  }
}

// ---------------- Q kernel: Qp[g][b][k] partial quadratic forms ----------------
__global__ __launch_bounds__(256) void qkern(const float* __restrict__ X, const float* __restrict__ A,
                                             float* __restrict__ Qp) {
  int g = blockIdx.x;
  int btile = blockIdx.y;
  __shared__ float Xs[4][1024];
  __shared__ float Cs[4][4096];
  int tid = threadIdx.x;
  int wave = tid >> 6, lane = tid & 63;
  for (int t = tid; t < 4096; t += 256) {
    int bb = t >> 10, e = t & 1023;
    Xs[bb][e] = X[(size_t)(btile * 4 + bb) * 1024 + e];
  }
  float regQ[4][8];
#pragma unroll
  for (int bb = 0; bb < 4; ++bb)
#pragma unroll
    for (int kk = 0; kk < 8; ++kk) regQ[bb][kk] = 0.f;

  int a0 = (tid >> 4) << 2;
  int v0 = (tid & 15) << 2;
  for (int dd = 0; dd < 4; ++dd) {
    int d = g + (dd << 2);
    __syncthreads();
    for (int bb = 0; bb < 4; ++bb) {
      float4 r0 = {0,0,0,0}, r1 = {0,0,0,0}, r2 = {0,0,0,0}, r3 = {0,0,0,0};
      for (int j = 0; j + d < 16; ++j) {
        const float4 xa = *(const float4*)&Xs[bb][j * 64 + a0];
        const float4 xv = *(const float4*)&Xs[bb][(j + d) * 64 + v0];
        r0.x += xa.x * xv.x; r0.y += xa.x * xv.y; r0.z += xa.x * xv.z; r0.w += xa.x * xv.w;
        r1.x += xa.y * xv.x; r1.y += xa.y * xv.y; r1.z += xa.y * xv.z; r1.w += xa.y * xv.w;
        r2.x += xa.z * xv.x; r2.y += xa.z * xv.y; r2.z += xa.z * xv.z; r2.w += xa.z * xv.w;
        r3.x += xa.w * xv.x; r3.y += xa.w * xv.y; r3.z += xa.w * xv.z; r3.w += xa.w * xv.w;
      }
      *(float4*)&Cs[bb][(a0 + 0) * 64 + v0] = r0;
      *(float4*)&Cs[bb][(a0 + 1) * 64 + v0] = r1;
      *(float4*)&Cs[bb][(a0 + 2) * 64 + v0] = r2;
      *(float4*)&Cs[bb][(a0 + 3) * 64 + v0] = r3;
    }
    __syncthreads();
    float w = (d == 0) ? 1.f : 2.f;
    for (int ch = 0; ch < 16; ++ch) {
      int e4 = (ch * 64 + lane) << 2;
      float4 cv[4];
#pragma unroll
      for (int bb = 0; bb < 4; ++bb) {
        float4 t4 = *(const float4*)&Cs[bb][e4];
        cv[bb].x = w * t4.x; cv[bb].y = w * t4.y; cv[bb].z = w * t4.z; cv[bb].w = w * t4.w;
      }
#pragma unroll
      for (int kk = 0; kk < 8; ++kk) {
        int k = wave + (kk << 2);
        const float4 av = *(const float4*)(A + (((size_t)(d * K_ + k)) << 12) + e4);
#pragma unroll
        for (int bb = 0; bb < 4; ++bb)
          regQ[bb][kk] += av.x * cv[bb].x + av.y * cv[bb].y + av.z * cv[bb].z + av.w * cv[bb].w;
      }
    }
  }
#pragma unroll
  for (int bb = 0; bb < 4; ++bb)
#pragma unroll
    for (int kk = 0; kk < 8; ++kk) {
      float v = regQ[bb][kk];
      for (int off = 32; off; off >>= 1) v += __shfl_xor(v, off);
      regQ[bb][kk] = v;
    }
  if (lane == 0) {
    int b = btile * 4;
#pragma unroll
    for (int bb = 0; bb < 4; ++bb)
#pragma unroll
      for (int kk = 0; kk < 8; ++kk)
        Qp[((size_t)(g * B_ + b + bb) << 5) + (wave + (kk << 2))] = regQ[bb][kk];
  }
}

// ---------------- LU panel (nb=32) v8: LDS slab, runtime loop, deferred pivoting ----------------
// 512 threads; thread t owns slab rows t and t+512. Rows never move: pivot rows are
// marked used and staged to l11s/bufP by threads 0..31 in parallel (p is uniform).
// 2 barriers/step; compact loop body stays I$-hot. Full-column partial pivoting
// (same pivot choices as the swap-based versions). Fused TRSM epilogue -> Uws.
__global__ __launch_bounds__(512, 1) void panelk(float* __restrict__ M, int* __restrict__ rowmap,
                                                 float* __restrict__ logdet, float* __restrict__ Uws,
                                                 int j0) {
  int k = blockIdx.x;
  float* Mk = M + ((size_t)k << 20);
  int* rmk = rowmap + (k << 10);
  int m = N_ - j0;
  int t = threadIdx.x;
  int lane = t & 63, wid = t >> 6;   // 8 waves

  __shared__ __align__(16) float slab[1024 * 36];   // 144 KB, stride 144B (f4-aligned rows)
  __shared__ __align__(16) float l11s[32 * 36];     // factor rows (TRSM + diag)
  __shared__ __align__(16) float bufP[32];          // masked pivot row (0 for c <= jj)
  __shared__ int smapU[32];
  __shared__ int pivslot[32];
  __shared__ float candv[8];
  __shared__ int candi[8];

  int oA = -1, oB = -1;
  bool aA = (t < m), aB = (t + 512 < m);
  if (aA) oA = rmk[j0 + t];
  if (aB) oB = rmk[j0 + 512 + t];
  if (aA) {
    const float* src = Mk + (size_t)oA * N_ + j0;
#pragma unroll
    for (int c4 = 0; c4 < 8; ++c4) *(float4*)&slab[t * 36 + c4 * 4] = *(const float4*)(src + c4 * 4);
  }
  if (aB) {
    const float* src = Mk + (size_t)oB * N_ + j0;
#pragma unroll
    for (int c4 = 0; c4 < 8; ++c4) *(float4*)&slab[(t + 512) * 36 + c4 * 4] = *(const float4*)(src + c4 * 4);
  }
  bool uA = false, uB = false;
  __syncthreads();

  // prologue: candidates for column 0
  {
    float bv = aA ? fabsf(slab[t * 36]) : -1.f;
    int bi = t;
    if (aB) { float v = fabsf(slab[(t + 512) * 36]); if (v > bv) { bv = v; bi = t + 512; } }
#pragma unroll
    for (int off = 32; off; off >>= 1) {
      float ov = __shfl_xor(bv, off);
      int oi = __shfl_xor(bi, off);
      if (ov > bv) { bv = ov; bi = oi; }
    }
    if (lane == 0) { candv[wid] = bv; candi[wid] = bi; }
  }
  __syncthreads();

#pragma unroll 1
  for (int jj = 0; jj < 32; ++jj) {
    // ---- redundant reduce of 8 wave candidates: uniform pivot slot p ----
    float cvv = candv[0]; int p = candi[0];
#pragma unroll
    for (int w = 1; w < 8; ++w) { float v = candv[w]; if (v > cvv) { cvv = v; p = candi[w]; } }
    // ---- parallel stage of pivot row p (conflict-free: consecutive addresses) ----
    if (t < 32) {
      float v = slab[p * 36 + t];
      l11s[jj * 36 + t] = v;
      bufP[t] = (t > jj) ? v : 0.f;
    }
    if (t < 8)
      *(float4*)(Mk + (size_t)(j0 + jj) * N_ + j0 + t * 4) = *(const float4*)&slab[p * 36 + t * 4];
    if (t == (p & 511)) {
      if (p >> 9) { uB = true; smapU[jj] = oB; } else { uA = true; smapU[jj] = oA; }
      pivslot[jj] = p;
    }
    __syncthreads();
    // ---- rank-1 update on unused rows + merged next-column scan ----
    float sinv = 1.0f / l11s[jj * 36 + jj];
    int g0 = jj >> 2;
    float bv = -1.f; int bi = t;
    if (aA && !uA) {
      int base = t * 36;
      float mult = slab[base + jj] * sinv;
      for (int g = g0; g < 8; ++g) {
        float4 cur = *(const float4*)&slab[base + g * 4];
        float4 pm = *(const float4*)&bufP[g * 4];
        cur.x -= mult * pm.x; cur.y -= mult * pm.y; cur.z -= mult * pm.z; cur.w -= mult * pm.w;
        *(float4*)&slab[base + g * 4] = cur;
      }
      slab[base + jj] = mult;
      if (jj < 31) bv = fabsf(slab[base + jj + 1]);
    }
    if (aB && !uB) {
      int base = (t + 512) * 36;
      float mult = slab[base + jj] * sinv;
      for (int g = g0; g < 8; ++g) {
        float4 cur = *(const float4*)&slab[base + g * 4];
        float4 pm = *(const float4*)&bufP[g * 4];
        cur.x -= mult * pm.x; cur.y -= mult * pm.y; cur.z -= mult * pm.z; cur.w -= mult * pm.w;
        *(float4*)&slab[base + g * 4] = cur;
      }
      slab[base + jj] = mult;
      if (jj < 31) { float v = fabsf(slab[base + jj + 1]); if (v > bv) { bv = v; bi = t + 512; } }
    }
    if (jj < 31) {
#pragma unroll
      for (int off = 32; off; off >>= 1) {
        float ov = __shfl_xor(bv, off);
        int oi = __shfl_xor(bi, off);
        if (ov > bv) { bv = ov; bi = oi; }
      }
      if (lane == 0) { candv[wid] = bv; candi[wid] = bi; }
    }
    __syncthreads();
  }

  // ---- logdet from factor diagonals (parallel logf) ----
  if (t < 32) {
    float lv = logf(fabsf(l11s[t * 36 + t]));
#pragma unroll
    for (int off = 16; off; off >>= 1) lv += __shfl_down(lv, off, 32);
    if (t == 0) logdet[k] += lv;
    rmk[j0 + t] = smapU[t];
  }
  // ---- L21 export: position = 32 + g - (#pivot slots < g) ----
  if (aA && !uA) {
    int cnt = 0;
#pragma unroll
    for (int j = 0; j < 32; ++j) cnt += (pivslot[j] < t) ? 1 : 0;
    int pos = 32 + t - cnt;
    float* dst = Mk + (size_t)(j0 + pos) * N_ + j0;
#pragma unroll
    for (int c4 = 0; c4 < 8; ++c4) *(float4*)(dst + c4 * 4) = *(const float4*)&slab[t * 36 + c4 * 4];
    rmk[j0 + pos] = oA;
  }
  if (aB && !uB) {
    int g = t + 512;
    int cnt = 0;
#pragma unroll
    for (int j = 0; j < 32; ++j) cnt += (pivslot[j] < g) ? 1 : 0;
    int pos = 32 + g - cnt;
    float* dst = Mk + (size_t)(j0 + pos) * N_ + j0;
#pragma unroll
    for (int c4 = 0; c4 < 8; ++c4) *(float4*)(dst + c4 * 4) = *(const float4*)&slab[g * 36 + c4 * 4];
    rmk[j0 + pos] = oB;
  }

  // ---- fused TRSM: U12 = L11^{-1} P A12, one column per thread -> Uws ----
  int mprime = m - 32;
  float* Uk = Uws + ((size_t)k << 15);
  for (int cx = t; cx < mprime; cx += 512) {
    int col = j0 + 32 + cx;
    float u[32];
#pragma unroll
    for (int rr = 0; rr < 32; ++rr) {
      float av = Mk[(size_t)smapU[rr] * N_ + col];
#pragma unroll
      for (int tt = 0; tt < 32; ++tt) { if (tt < rr) av -= l11s[rr * 36 + tt] * u[tt]; }
      u[rr] = av;
      Uk[(rr << 10) + col] = av;
    }
  }
}

// ---------------- trailing GEMM update, 128x128 C tile, C-early-load ----------------
__global__ __launch_bounds__(256) void updatek(float* __restrict__ M, const int* __restrict__ rowmap,
                                               const float* __restrict__ Uws, int j0) {
  int k = blockIdx.z;
  int mprime = N_ - j0 - 32;
  int r0 = blockIdx.y << 7;
  int c0 = blockIdx.x << 7;
  float* Mk = M + ((size_t)k << 20);
  const int* rmk = rowmap + (k << 10);
  __shared__ float LtT[32 * 132];
  __shared__ float Ut[32 * 132];
  __shared__ int rowL[128];
  int tid = threadIdx.x;

  if (tid < 128) rowL[tid] = (r0 + tid < mprime) ? rmk[j0 + 32 + r0 + tid] : -1;
  for (int x = tid; x < 1024; x += 256) {
    int rI = x >> 3, q = (x & 7) << 2;
    float4 v = {0.f, 0.f, 0.f, 0.f};
    if (r0 + rI < mprime) v = *(const float4*)(Mk + (size_t)(j0 + 32 + r0 + rI) * N_ + j0 + q);
    LtT[(q + 0) * 132 + rI] = v.x;
    LtT[(q + 1) * 132 + rI] = v.y;
    LtT[(q + 2) * 132 + rI] = v.z;
    LtT[(q + 3) * 132 + rI] = v.w;
  }
  {
    const float* Uk = Uws + ((size_t)k << 15) + j0 + 32 + c0;
    for (int x = tid; x < 1024; x += 256) {
      int rr = x >> 5, c4 = (x & 31) << 2;
      float4 v = {0.f, 0.f, 0.f, 0.f};
      if (c0 + c4 < mprime) v = *(const float4*)(Uk + (rr << 10) + c4);
      *(float4*)&Ut[rr * 132 + c4] = v;
    }
  }
  __syncthreads();

  int tx = tid & 15, ty = tid >> 4;
  int cc = c0 + (tx << 2);

  float4 cur[2][2][4];
#pragma unroll
  for (int ri = 0; ri < 2; ++ri)
#pragma unroll
    for (int r = 0; r < 4; ++r) {
      int lr = (ty << 2) + r + (ri << 6);
      int pr = rowL[lr];
#pragma unroll
      for (int ci = 0; ci < 2; ++ci) {
        int lc = cc + (ci << 6);
        if (pr >= 0 && lc < mprime)
          cur[ri][ci][r] = *(const float4*)(Mk + (size_t)pr * N_ + j0 + 32 + lc);
        else
          cur[ri][ci][r] = make_float4(0.f, 0.f, 0.f, 0.f);
      }
    }

#define FMS4(dst, s, b4) dst.x -= (s) * b4.x; dst.y -= (s) * b4.y; dst.z -= (s) * b4.z; dst.w -= (s) * b4.w;
#pragma unroll 8
  for (int tk = 0; tk < 32; ++tk) {
    float4 aL = *(const float4*)&LtT[tk * 132 + (ty << 2)];
    float4 aH = *(const float4*)&LtT[tk * 132 + (ty << 2) + 64];
    float4 bL = *(const float4*)&Ut[tk * 132 + (tx << 2)];
    float4 bH = *(const float4*)&Ut[tk * 132 + (tx << 2) + 64];
    FMS4(cur[0][0][0], aL.x, bL) FMS4(cur[0][0][1], aL.y, bL) FMS4(cur[0][0][2], aL.z, bL) FMS4(cur[0][0][3], aL.w, bL)
    FMS4(cur[0][1][0], aL.x, bH) FMS4(cur[0][1][1], aL.y, bH) FMS4(cur[0][1][2], aL.z, bH) FMS4(cur[0][1][3], aL.w, bH)
    FMS4(cur[1][0][0], aH.x, bL) FMS4(cur[1][0][1], aH.y, bL) FMS4(cur[1][0][2], aH.z, bL) FMS4(cur[1][0][3], aH.w, bL)
    FMS4(cur[1][1][0], aH.x, bH) FMS4(cur[1][1][1], aH.y, bH) FMS4(cur[1][1][2], aH.z, bH) FMS4(cur[1][1][3], aH.w, bH)
  }
#undef FMS4

#pragma unroll
  for (int ri = 0; ri < 2; ++ri)
#pragma unroll
    for (int r = 0; r < 4; ++r) {
      int lr = (ty << 2) + r + (ri << 6);
      int pr = rowL[lr];
      if (pr < 0) continue;
      float* rowp = Mk + (size_t)pr * N_ + j0 + 32;
#pragma unroll
      for (int ci = 0; ci < 2; ++ci) {
        int lc = cc + (ci << 6);
        if (lc < mprime) *(float4*)(rowp + lc) = cur[ri][ci][r];
      }
    }
}

// ---------------- final: cross term, lle, softmax ----------------
__global__ __launch_bounds__(256) void finalk(const float* __restrict__ X, const float* __restrict__ rbuf,
                                              const float* __restrict__ cterm, const float* __restrict__ logdet,
                                              const float* __restrict__ Qp, float* __restrict__ out) {
  int b = blockIdx.x;
  __shared__ float Xs[1024];
  __shared__ float lleS[32];
  int tid = threadIdx.x, wave = tid >> 6, lane = tid & 63;
  for (int i = tid; i < 1024; i += 256) Xs[i] = X[(size_t)b * 1024 + i];
  __syncthreads();
#pragma unroll
  for (int kk = 0; kk < 8; ++kk) {
    int k = wave + (kk << 2);
    const float* rk = rbuf + (size_t)k * 1024;
    float acc = 0.f;
#pragma unroll
    for (int ch = 0; ch < 4; ++ch) {
      int e4 = (ch * 64 + lane) << 2;
      const float4 rv = *(const float4*)(rk + e4);
      const float4 xv = *(const float4*)&Xs[e4];
      acc += rv.x * xv.x + rv.y * xv.y + rv.z * xv.z + rv.w * xv.w;
    }
    for (int off = 32; off; off >>= 1) acc += __shfl_xor(acc, off);
    if (lane == 0) {
      float Qv = 0.f;
#pragma unroll
      for (int g = 0; g < 4; ++g) Qv += Qp[((size_t)(g * B_ + b) << 5) + k];
      float P1 = Qv - 2.f * acc + cterm[k];
      lleS[k] = -0.5f * P1 + logdet[k];
    }
  }
  __syncthreads();
  if (wave == 0) {
    float v = lleS[lane & 31];
    float mx = v;
    for (int off = 16; off; off >>= 1) mx = fmaxf(mx, __shfl_xor(mx, off));
    float e = expf(v - mx);
    float s = e;
    for (int off = 16; off; off >>= 1) s += __shfl_xor(s, off);
    if (lane < 32) out[b * 32 + lane] = e / s;
  }
}

extern "C" void kernel_launch(void* const* d_in, const int* in_sizes, int n_in,
                              void* d_out, int out_size, void* d_ws, size_t ws_size,
                              hipStream_t stream) {
  const float* X  = (const float*)d_in[0];
  const float* mu = (const float*)d_in[1];
  const float* A  = (const float*)d_in[2];
  float* out = (float*)d_out;
  float* ws  = (float*)d_ws;

  if (ws_size < 138936576ull) {   // 128 MB M + maps + 4 MB U stripe
    hipMemsetAsync(d_out, 0, (size_t)out_size * sizeof(float), stream);
    return;
  }

  float* M      = ws;                        // 33554432 floats (128 MB)
  int*   rowmap = (int*)(ws + 33554432);     // 32768 ints
  float* logdet = ws + 33587200;             // 32
  float* rbuf   = ws + 33587232;             // 32768
  float* cterm  = ws + 33620000;             // 32
  float* Qp     = ws + 33620032;             // 65536
  float* Uws    = ws + 33685568;             // 32*32*1024 = 1048576 floats (4 MB)

  initk<<<dim3(128), dim3(256), 0, stream>>>(rowmap, logdet);
  buildM<<<dim3(16, 16, 32), dim3(256), 0, stream>>>(A, M);
  prepk<<<dim3(32), dim3(256), 0, stream>>>(A, mu, rbuf, cterm);
  qkern<<<dim3(4, 128), dim3(256), 0, stream>>>(X, A, Qp);

  for (int s = 0; s < 32; ++s) {
    int j0 = s * 32;
    panelk<<<dim3(32), dim3(512), 0, stream>>>(M, rowmap, logdet, Uws, j0);
    int mprime = N_ - j0 - 32;
    if (mprime > 0) {
      int mt = (mprime + 127) >> 7;
      updatek<<<dim3(mt, mt, 32), dim3(256), 0, stream>>>(M, rowmap, Uws, j0);
    }
  }

  finalk<<<dim3(512), dim3(256), 0, stream>>>(X, rbuf, cterm, logdet, Qp, out);
}

// Round 11
// 2710.530 us; speedup vs baseline: 2.9208x; 1.2070x over previous
//
#include <hip/hip_runtime.h>
#include <math.h>

static constexpr int B_ = 512;
static constexpr int T_ = 16;
static constexpr int S_ = 64;
static constexpr int K_ = 32;
static constexpr int N_ = 1024;   // T_*S_

// ---------------- init: rowmap identity + logdet zero ----------------
__global__ void initk(int* __restrict__ rowmap, float* __restrict__ logdet) {
  int idx = blockIdx.x * 256 + threadIdx.x;
  if (idx < K_ * N_) rowmap[idx] = idx & (N_ - 1);
  if (idx < K_) logdet[idx] = 0.f;
}

// ---------------- build block-Toeplitz M[k][row][col], LDS-transpose version ----
__global__ __launch_bounds__(256) void buildM(const float* __restrict__ A, float* __restrict__ M) {
  int k = blockIdx.z, i = blockIdx.y, j = blockIdx.x;
  int d = i - j;
  int ad = d >= 0 ? d : -d;
  const float* Ad = A + ((size_t)(ad * K_ + k) << 12);
  float* out = M + ((size_t)k << 20) + (size_t)(i * 64) * N_ + j * 64;
  int tid = threadIdx.x;
  if (d < 0) {
    for (int x = tid; x < 1024; x += 256) {
      int a = x >> 4, b4 = (x & 15) << 2;
      *(float4*)(out + (size_t)a * N_ + b4) = *(const float4*)(Ad + a * 64 + b4);
    }
  } else {
    __shared__ float ts[64][65];
    for (int x = tid; x < 1024; x += 256) {
      int r = x >> 4, c4 = (x & 15) << 2;
      float4 v = *(const float4*)(Ad + r * 64 + c4);
      ts[c4 + 0][r] = v.x; ts[c4 + 1][r] = v.y; ts[c4 + 2][r] = v.z; ts[c4 + 3][r] = v.w;
    }
    __syncthreads();
    for (int x = tid; x < 1024; x += 256) {
      int a = x >> 4, b4 = (x & 15) << 2;
      float4 v;
      v.x = ts[a][b4 + 0]; v.y = ts[a][b4 + 1]; v.z = ts[a][b4 + 2]; v.w = ts[a][b4 + 3];
      *(float4*)(out + (size_t)a * N_ + b4) = v;
    }
  }
}

// ---------------- prep: r[k][j][s] and cterm[k] ----------------
__global__ __launch_bounds__(256) void prepk(const float* __restrict__ A, const float* __restrict__ mu,
                                             float* __restrict__ rbuf, float* __restrict__ cterm) {
  int k = blockIdx.x;
  __shared__ float smu[64];
  __shared__ float sp[1024], sq[1024];
  int tid = threadIdx.x;
  if (tid < 64) smu[tid] = mu[k * 64 + tid];
  __syncthreads();
  for (int idx = tid; idx < 1024; idx += 256) {
    int d = idx >> 6, s = idx & 63;
    const float* Ad = A + ((size_t)(d * K_ + k) << 12);
    float ap = 0.f, aq = 0.f;
    for (int s2 = 0; s2 < 64; ++s2) {
      ap += Ad[s * 64 + s2] * smu[s2];
      aq += Ad[s2 * 64 + s] * smu[s2];
    }
    sp[idx] = ap; sq[idx] = aq;
  }
  __syncthreads();
  for (int idx = tid; idx < 1024; idx += 256) {
    int j = idx >> 6, s = idx & 63;
    float acc = 0.5f * (sp[s] + sq[s]);
    for (int d = 1; d < 16; ++d) {
      if (d <= 15 - j) acc += sp[d * 64 + s];
      if (d <= j)      acc += sq[d * 64 + s];
    }
    rbuf[k * 1024 + idx] = acc;
  }
  if (tid < 64) {
    float a = 16.f * sp[tid];
    for (int d = 1; d < 16; ++d) a += 2.f * (float)(16 - d) * sp[d * 64 + tid];
    a *= smu[tid];
    for (int off = 32; off; off >>= 1) a += __shfl_xor(a, off);
    if (tid == 0) cterm[k] = a;
  }
}

// ---------------- Q kernel: Qp[g][b][k] partial quadratic forms ----------------
__global__ __launch_bounds__(256) void qkern(const float* __restrict__ X, const float* __restrict__ A,
                                             float* __restrict__ Qp) {
  int g = blockIdx.x;
  int btile = blockIdx.y;
  __shared__ float Xs[4][1024];
  __shared__ float Cs[4][4096];
  int tid = threadIdx.x;
  int wave = tid >> 6, lane = tid & 63;
  for (int t = tid; t < 4096; t += 256) {
    int bb = t >> 10, e = t & 1023;
    Xs[bb][e] = X[(size_t)(btile * 4 + bb) * 1024 + e];
  }
  float regQ[4][8];
#pragma unroll
  for (int bb = 0; bb < 4; ++bb)
#pragma unroll
    for (int kk = 0; kk < 8; ++kk) regQ[bb][kk] = 0.f;

  int a0 = (tid >> 4) << 2;
  int v0 = (tid & 15) << 2;
  for (int dd = 0; dd < 4; ++dd) {
    int d = g + (dd << 2);
    __syncthreads();
    for (int bb = 0; bb < 4; ++bb) {
      float4 r0 = {0,0,0,0}, r1 = {0,0,0,0}, r2 = {0,0,0,0}, r3 = {0,0,0,0};
      for (int j = 0; j + d < 16; ++j) {
        const float4 xa = *(const float4*)&Xs[bb][j * 64 + a0];
        const float4 xv = *(const float4*)&Xs[bb][(j + d) * 64 + v0];
        r0.x += xa.x * xv.x; r0.y += xa.x * xv.y; r0.z += xa.x * xv.z; r0.w += xa.x * xv.w;
        r1.x += xa.y * xv.x; r1.y += xa.y * xv.y; r1.z += xa.y * xv.z; r1.w += xa.y * xv.w;
        r2.x += xa.z * xv.x; r2.y += xa.z * xv.y; r2.z += xa.z * xv.z; r2.w += xa.z * xv.w;
        r3.x += xa.w * xv.x; r3.y += xa.w * xv.y; r3.z += xa.w * xv.z; r3.w += xa.w * xv.w;
      }
      *(float4*)&Cs[bb][(a0 + 0) * 64 + v0] = r0;
      *(float4*)&Cs[bb][(a0 + 1) * 64 + v0] = r1;
      *(float4*)&Cs[bb][(a0 + 2) * 64 + v0] = r2;
      *(float4*)&Cs[bb][(a0 + 3) * 64 + v0] = r3;
    }
    __syncthreads();
    float w = (d == 0) ? 1.f : 2.f;
    for (int ch = 0; ch < 16; ++ch) {
      int e4 = (ch * 64 + lane) << 2;
      float4 cv[4];
#pragma unroll
      for (int bb = 0; bb < 4; ++bb) {
        float4 t4 = *(const float4*)&Cs[bb][e4];
        cv[bb].x = w * t4.x; cv[bb].y = w * t4.y; cv[bb].z = w * t4.z; cv[bb].w = w * t4.w;
      }
#pragma unroll
      for (int kk = 0; kk < 8; ++kk) {
        int k = wave + (kk << 2);
        const float4 av = *(const float4*)(A + (((size_t)(d * K_ + k)) << 12) + e4);
#pragma unroll
        for (int bb = 0; bb < 4; ++bb)
          regQ[bb][kk] += av.x * cv[bb].x + av.y * cv[bb].y + av.z * cv[bb].z + av.w * cv[bb].w;
      }
    }
  }
#pragma unroll
  for (int bb = 0; bb < 4; ++bb)
#pragma unroll
    for (int kk = 0; kk < 8; ++kk) {
      float v = regQ[bb][kk];
      for (int off = 32; off; off >>= 1) v += __shfl_xor(v, off);
      regQ[bb][kk] = v;
    }
  if (lane == 0) {
    int b = btile * 4;
#pragma unroll
    for (int bb = 0; bb < 4; ++bb)
#pragma unroll
      for (int kk = 0; kk < 8; ++kk)
        Qp[((size_t)(g * B_ + b + bb) << 5) + (wave + (kk << 2))] = regQ[bb][kk];
  }
}

// ---------------- LU panel (nb=32) v10: R5 register rows, 2 barriers/step ----------------
// One thread per row (R5-proven layout, no spill). Per step:
// phase A: all threads redundantly reduce wave candidates (uniform p); owner
// stages pivot row to bufP, displaced row jj to bufJ. [barrier]
// phase B: adopt swaps; rank-1 update; merged scan of column jj+1. [barrier]
// Epilogue (R5 verbatim): logdet, l11s staging, dense export, fused TRSM -> Uws.
__global__ __launch_bounds__(1024, 1) void panelk(float* __restrict__ M, int* __restrict__ rowmap,
                                                  float* __restrict__ logdet, float* __restrict__ Uws,
                                                  int j0) {
  int k = blockIdx.x;
  float* Mk = M + ((size_t)k << 20);
  int* rmk = rowmap + (k << 10);
  int m = N_ - j0;
  int t = threadIdx.x;
  int bdim = blockDim.x;
  int lane = t & 63, wid = t >> 6;
  int nw = (bdim + 63) >> 6;

  __shared__ float bufP[32];
  __shared__ float bufJ[32];
  __shared__ int origP, origJ;
  __shared__ float candv[16];
  __shared__ int candi[16];
  __shared__ float l11s[32 * 33];
  __shared__ int smapU[32];

  float r[32];
  int myorig = -1;
  float mydiag = 1.f;
  bool act = (t < m);
  if (act) {
    myorig = rmk[j0 + t];
    const float* src = Mk + (size_t)myorig * N_ + j0;
#pragma unroll
    for (int c4 = 0; c4 < 8; ++c4) *(float4*)&r[c4 * 4] = *(const float4*)(src + c4 * 4);
  }

  // prologue: scan column 0
  {
    float bv = act ? fabsf(r[0]) : -1.f;
    int bi = t;
#pragma unroll
    for (int off = 32; off; off >>= 1) {
      float ov = __shfl_xor(bv, off);
      int oi = __shfl_xor(bi, off);
      if (ov > bv) { bv = ov; bi = oi; }
    }
    if (lane == 0) { candv[wid] = bv; candi[wid] = bi; }
  }
  __syncthreads();

#pragma unroll
  for (int jj = 0; jj < 32; ++jj) {
    // ---- phase A: redundant block reduce -> uniform p; stage pivot/displaced ----
    float cv = candv[0]; int p = candi[0];
    for (int w = 1; w < nw; ++w) { float v = candv[w]; if (v > cv) { cv = v; p = candi[w]; } }
    if (t == p) {
#pragma unroll
      for (int c4 = 0; c4 < 8; ++c4) *(float4*)&bufP[c4 * 4] = *(const float4*)&r[c4 * 4];
      origP = myorig;
    }
    if (p != jj && t == jj) {
#pragma unroll
      for (int c4 = 0; c4 < 8; ++c4) *(float4*)&bufJ[c4 * 4] = *(const float4*)&r[c4 * 4];
      origJ = myorig;
    }
    __syncthreads();
    // ---- phase B: adopt swaps; broadcast pivot row; rank-1 update; merged scan ----
    float pr[32];
#pragma unroll
    for (int c4 = 0; c4 < 8; ++c4) *(float4*)&pr[c4 * 4] = *(const float4*)&bufP[c4 * 4];
    if (p != jj) {
      if (t == jj) {
#pragma unroll
        for (int c = 0; c < 32; ++c) r[c] = pr[c];
        myorig = origP;
      } else if (t == p) {
#pragma unroll
        for (int c4 = 0; c4 < 8; ++c4) *(float4*)&r[c4 * 4] = *(const float4*)&bufJ[c4 * 4];
        myorig = origJ;
      }
    }
    float pv = pr[jj];
    if (t == jj) mydiag = pv;
    float sinv = 1.0f / pv;
    float bv = -1.f; int bi = t;
    if (act && t > jj) {
      float mult = r[jj] * sinv;
      r[jj] = mult;
#pragma unroll
      for (int c = jj + 1; c < 32; ++c) r[c] -= mult * pr[c];
      if (jj < 31) bv = fabsf(r[jj + 1]);
    }
    if (jj < 31) {
#pragma unroll
      for (int off = 32; off; off >>= 1) {
        float ov = __shfl_xor(bv, off);
        int oi = __shfl_xor(bi, off);
        if (ov > bv) { bv = ov; bi = oi; }
      }
      if (lane == 0) { candv[wid] = bv; candi[wid] = bi; }
    }
    __syncthreads();
  }

  // ---- logdet from saved diagonals ----
  if (t < 32) {
    float lv = logf(fabsf(mydiag));
#pragma unroll
    for (int off = 16; off; off >>= 1) lv += __shfl_down(lv, off, 32);
    if (t == 0) logdet[k] += lv;
  }
  // ---- stage L11\U11 + pivoted-row origins for the TRSM epilogue ----
  if (t < 32) {
#pragma unroll
    for (int c = 0; c < 32; ++c) l11s[t * 33 + c] = r[c];
    smapU[t] = myorig;
  }
  // ---- export L/U panel (pivoted order, dense) + rowmap writeback ----
  if (act) {
    float* dst = Mk + (size_t)(j0 + t) * N_ + j0;
#pragma unroll
    for (int c4 = 0; c4 < 8; ++c4) *(float4*)(dst + c4 * 4) = *(const float4*)&r[c4 * 4];
    rmk[j0 + t] = myorig;
  }
  __syncthreads();

  // ---- fused TRSM: U12 = L11^{-1} A12, one column per thread, solved ONCE ----
  int mprime = m - 32;
  if (t < mprime) {
    int col = j0 + 32 + t;
    float* Uk = Uws + ((size_t)k << 15);
    float u[32];
#pragma unroll
    for (int rr = 0; rr < 32; ++rr) {
      float av = Mk[(size_t)smapU[rr] * N_ + col];
#pragma unroll
      for (int tt = 0; tt < 32; ++tt) { if (tt < rr) av -= l11s[rr * 33 + tt] * u[tt]; }
      u[rr] = av;
      Uk[(rr << 10) + col] = av;
    }
  }
}

// ---------------- trailing GEMM update, 128x128 C tile, C-early-load ----------------
__global__ __launch_bounds__(256) void updatek(float* __restrict__ M, const int* __restrict__ rowmap,
                                               const float* __restrict__ Uws, int j0) {
  int k = blockIdx.z;
  int mprime = N_ - j0 - 32;
  int r0 = blockIdx.y << 7;
  int c0 = blockIdx.x << 7;
  float* Mk = M + ((size_t)k << 20);
  const int* rmk = rowmap + (k << 10);
  __shared__ float LtT[32 * 132];
  __shared__ float Ut[32 * 132];
  __shared__ int rowL[128];
  int tid = threadIdx.x;

  if (tid < 128) rowL[tid] = (r0 + tid < mprime) ? rmk[j0 + 32 + r0 + tid] : -1;
  for (int x = tid; x < 1024; x += 256) {
    int rI = x >> 3, q = (x & 7) << 2;
    float4 v = {0.f, 0.f, 0.f, 0.f};
    if (r0 + rI < mprime) v = *(const float4*)(Mk + (size_t)(j0 + 32 + r0 + rI) * N_ + j0 + q);
    LtT[(q + 0) * 132 + rI] = v.x;
    LtT[(q + 1) * 132 + rI] = v.y;
    LtT[(q + 2) * 132 + rI] = v.z;
    LtT[(q + 3) * 132 + rI] = v.w;
  }
  {
    const float* Uk = Uws + ((size_t)k << 15) + j0 + 32 + c0;
    for (int x = tid; x < 1024; x += 256) {
      int rr = x >> 5, c4 = (x & 31) << 2;
      float4 v = {0.f, 0.f, 0.f, 0.f};
      if (c0 + c4 < mprime) v = *(const float4*)(Uk + (rr << 10) + c4);
      *(float4*)&Ut[rr * 132 + c4] = v;
    }
  }
  __syncthreads();

  int tx = tid & 15, ty = tid >> 4;
  int cc = c0 + (tx << 2);

  // ---- C tile early load (hides RMW read latency under the GEMM) ----
  float4 cur[2][2][4];
#pragma unroll
  for (int ri = 0; ri < 2; ++ri)
#pragma unroll
    for (int r = 0; r < 4; ++r) {
      int lr = (ty << 2) + r + (ri << 6);
      int pr = rowL[lr];
#pragma unroll
      for (int ci = 0; ci < 2; ++ci) {
        int lc = cc + (ci << 6);
        if (pr >= 0 && lc < mprime)
          cur[ri][ci][r] = *(const float4*)(Mk + (size_t)pr * N_ + j0 + 32 + lc);
        else
          cur[ri][ci][r] = make_float4(0.f, 0.f, 0.f, 0.f);
      }
    }

#define FMS4(dst, s, b4) dst.x -= (s) * b4.x; dst.y -= (s) * b4.y; dst.z -= (s) * b4.z; dst.w -= (s) * b4.w;
#pragma unroll 8
  for (int tk = 0; tk < 32; ++tk) {
    float4 aL = *(const float4*)&LtT[tk * 132 + (ty << 2)];
    float4 aH = *(const float4*)&LtT[tk * 132 + (ty << 2) + 64];
    float4 bL = *(const float4*)&Ut[tk * 132 + (tx << 2)];
    float4 bH = *(const float4*)&Ut[tk * 132 + (tx << 2) + 64];
    FMS4(cur[0][0][0], aL.x, bL) FMS4(cur[0][0][1], aL.y, bL) FMS4(cur[0][0][2], aL.z, bL) FMS4(cur[0][0][3], aL.w, bL)
    FMS4(cur[0][1][0], aL.x, bH) FMS4(cur[0][1][1], aL.y, bH) FMS4(cur[0][1][2], aL.z, bH) FMS4(cur[0][1][3], aL.w, bH)
    FMS4(cur[1][0][0], aH.x, bL) FMS4(cur[1][0][1], aH.y, bL) FMS4(cur[1][0][2], aH.z, bL) FMS4(cur[1][0][3], aH.w, bL)
    FMS4(cur[1][1][0], aH.x, bH) FMS4(cur[1][1][1], aH.y, bH) FMS4(cur[1][1][2], aH.z, bH) FMS4(cur[1][1][3], aH.w, bH)
  }
#undef FMS4

#pragma unroll
  for (int ri = 0; ri < 2; ++ri)
#pragma unroll
    for (int r = 0; r < 4; ++r) {
      int lr = (ty << 2) + r + (ri << 6);
      int pr = rowL[lr];
      if (pr < 0) continue;
      float* rowp = Mk + (size_t)pr * N_ + j0 + 32;
#pragma unroll
      for (int ci = 0; ci < 2; ++ci) {
        int lc = cc + (ci << 6);
        if (lc < mprime) *(float4*)(rowp + lc) = cur[ri][ci][r];
      }
    }
}

// ---------------- final: cross term, lle, softmax ----------------
__global__ __launch_bounds__(256) void finalk(const float* __restrict__ X, const float* __restrict__ rbuf,
                                              const float* __restrict__ cterm, const float* __restrict__ logdet,
                                              const float* __restrict__ Qp, float* __restrict__ out) {
  int b = blockIdx.x;
  __shared__ float Xs[1024];
  __shared__ float lleS[32];
  int tid = threadIdx.x, wave = tid >> 6, lane = tid & 63;
  for (int i = tid; i < 1024; i += 256) Xs[i] = X[(size_t)b * 1024 + i];
  __syncthreads();
#pragma unroll
  for (int kk = 0; kk < 8; ++kk) {
    int k = wave + (kk << 2);
    const float* rk = rbuf + (size_t)k * 1024;
    float acc = 0.f;
#pragma unroll
    for (int ch = 0; ch < 4; ++ch) {
      int e4 = (ch * 64 + lane) << 2;
      const float4 rv = *(const float4*)(rk + e4);
      const float4 xv = *(const float4*)&Xs[e4];
      acc += rv.x * xv.x + rv.y * xv.y + rv.z * xv.z + rv.w * xv.w;
    }
    for (int off = 32; off; off >>= 1) acc += __shfl_xor(acc, off);
    if (lane == 0) {
      float Qv = 0.f;
#pragma unroll
      for (int g = 0; g < 4; ++g) Qv += Qp[((size_t)(g * B_ + b) << 5) + k];
      float P1 = Qv - 2.f * acc + cterm[k];
      lleS[k] = -0.5f * P1 + logdet[k];
    }
  }
  __syncthreads();
  if (wave == 0) {
    float v = lleS[lane & 31];
    float mx = v;
    for (int off = 16; off; off >>= 1) mx = fmaxf(mx, __shfl_xor(mx, off));
    float e = expf(v - mx);
    float s = e;
    for (int off = 16; off; off >>= 1) s += __shfl_xor(s, off);
    if (lane < 32) out[b * 32 + lane] = e / s;
  }
}

extern "C" void kernel_launch(void* const* d_in, const int* in_sizes, int n_in,
                              void* d_out, int out_size, void* d_ws, size_t ws_size,
                              hipStream_t stream) {
  const float* X  = (const float*)d_in[0];
  const float* mu = (const float*)d_in[1];
  const float* A  = (const float*)d_in[2];
  float* out = (float*)d_out;
  float* ws  = (float*)d_ws;

  if (ws_size < 138936576ull) {   // 128 MB M + maps + 4 MB U stripe
    hipMemsetAsync(d_out, 0, (size_t)out_size * sizeof(float), stream);
    return;
  }

  float* M      = ws;                        // 33554432 floats (128 MB)
  int*   rowmap = (int*)(ws + 33554432);     // 32768 ints
  float* logdet = ws + 33587200;             // 32
  float* rbuf   = ws + 33587232;             // 32768
  float* cterm  = ws + 33620000;             // 32
  float* Qp     = ws + 33620032;             // 65536
  float* Uws    = ws + 33685568;             // 32*32*1024 = 1048576 floats (4 MB)

  initk<<<dim3(128), dim3(256), 0, stream>>>(rowmap, logdet);
  buildM<<<dim3(16, 16, 32), dim3(256), 0, stream>>>(A, M);
  prepk<<<dim3(32), dim3(256), 0, stream>>>(A, mu, rbuf, cterm);
  qkern<<<dim3(4, 128), dim3(256), 0, stream>>>(X, A, Qp);

  for (int s = 0; s < 32; ++s) {
    int j0 = s * 32;
    int m = N_ - j0;
    int bt = ((m + 63) >> 6) << 6;           // threads = rows, rounded to wave
    panelk<<<dim3(32), dim3(bt), 0, stream>>>(M, rowmap, logdet, Uws, j0);
    int mprime = m - 32;
    if (mprime > 0) {
      int mt = (mprime + 127) >> 7;
      updatek<<<dim3(mt, mt, 32), dim3(256), 0, stream>>>(M, rowmap, Uws, j0);
    }
  }

  finalk<<<dim3(512), dim3(256), 0, stream>>>(X, rbuf, cterm, logdet, Qp, out);
}